// Round 8
// baseline (13420.526 us; speedup 1.0000x reference)
//
#include <hip/hip_runtime.h>
#include <math.h>

// Problem constants
#define Hn     1024
#define Bn     256
#define Tn     128
#define Vn     16384
#define DELTAn 16
#define Kn     5
#define QLn    128

typedef _Float16 h8 __attribute__((ext_vector_type(8)));
typedef _Float16 h4 __attribute__((ext_vector_type(4)));
typedef float    f32x4 __attribute__((ext_vector_type(4)));

#define MFMA16(a, b, c) __builtin_amdgcn_mfma_f32_16x16x32_f16(a, b, c, 0, 0, 0)

// Per-matrix fragment region size (N=4096, K=1024)
#define WFRAG_4096 8388608

// ---------------------------------------------------------------------------
// Fragment-shuffle weight conversion: W (N x 1024 fp32, row-major) ->
// chunk (gb, ks) = 64 lanes x 8 f16, hi plane then lo plane.
// lane l holds W[gb*16 + (l&15)][ks*32 + (l>>4)*8 + j], j=0..7.
// ---------------------------------------------------------------------------
__global__ __launch_bounds__(256) void wconv_frag(
    const float* __restrict__ W, _Float16* __restrict__ wf, int ngb)
{
    int wid  = (blockIdx.x * 256 + threadIdx.x) >> 6;
    int lane = threadIdx.x & 63;
    int gb = wid >> 5, ks = wid & 31;
    if (gb >= ngb) return;
    const float* src = W + (size_t)(gb * 16 + (lane & 15)) * 1024 + ks * 32 + (lane >> 4) * 8;
    float4 v0 = *(const float4*)src;
    float4 v1 = *(const float4*)(src + 4);
    float vv[8] = {v0.x, v0.y, v0.z, v0.w, v1.x, v1.y, v1.z, v1.w};
    h8 vh, vl;
    #pragma unroll
    for (int j = 0; j < 8; ++j) {
        _Float16 hh = (_Float16)vv[j];
        vh[j] = hh;
        vl[j] = (_Float16)(vv[j] - (float)hh);
    }
    _Float16* dst = wf + ((size_t)(gb * 32 + ks) * 2) * 512 + lane * 8;
    *(h8*)dst        = vh;
    *(h8*)(dst + 512) = vl;
}

// ---------------------------------------------------------------------------
// Big-tile fp32 GEMM (efc1 only, K=64): 128x128 tile, 8x8 microtile.
// ---------------------------------------------------------------------------
__global__ __launch_bounds__(256) void gemm_nt_128(
    const float* __restrict__ A, int lda, const float* __restrict__ W, int K,
    const float* __restrict__ bias, _Float16* __restrict__ yhi,
    _Float16* __restrict__ ylo, int ldy)
{
    __shared__ float As[16 * 132];
    __shared__ float Bs[16 * 132];
    const int bm   = blockIdx.y << 7;
    const int bn   = blockIdx.x << 7;
    const int tid  = threadIdx.x;
    const int tx   = (tid & 15) << 3;
    const int ty   = (tid >> 4) << 3;
    const int lrow = tid >> 1;
    const int lk   = (tid & 1) << 3;

    float acc[8][8] = {};
    const float* arow = A + (size_t)(bm + lrow) * lda + lk;
    const float* brow = W + (size_t)(bn + lrow) * K   + lk;

    for (int kt = 0; kt < K; kt += 16) {
        float4 a0 = *(const float4*)(arow + kt);
        float4 a1 = *(const float4*)(arow + kt + 4);
        float4 b0 = *(const float4*)(brow + kt);
        float4 b1 = *(const float4*)(brow + kt + 4);
        __syncthreads();
        As[(lk + 0) * 132 + lrow] = a0.x; As[(lk + 1) * 132 + lrow] = a0.y;
        As[(lk + 2) * 132 + lrow] = a0.z; As[(lk + 3) * 132 + lrow] = a0.w;
        As[(lk + 4) * 132 + lrow] = a1.x; As[(lk + 5) * 132 + lrow] = a1.y;
        As[(lk + 6) * 132 + lrow] = a1.z; As[(lk + 7) * 132 + lrow] = a1.w;
        Bs[(lk + 0) * 132 + lrow] = b0.x; Bs[(lk + 1) * 132 + lrow] = b0.y;
        Bs[(lk + 2) * 132 + lrow] = b0.z; Bs[(lk + 3) * 132 + lrow] = b0.w;
        Bs[(lk + 4) * 132 + lrow] = b1.x; Bs[(lk + 5) * 132 + lrow] = b1.y;
        Bs[(lk + 6) * 132 + lrow] = b1.z; Bs[(lk + 7) * 132 + lrow] = b1.w;
        __syncthreads();
        #pragma unroll
        for (int k = 0; k < 16; ++k) {
            float4 x0 = *(const float4*)(As + k * 132 + ty);
            float4 x1 = *(const float4*)(As + k * 132 + ty + 4);
            float4 y0 = *(const float4*)(Bs + k * 132 + tx);
            float4 y1 = *(const float4*)(Bs + k * 132 + tx + 4);
            float av[8] = {x0.x, x0.y, x0.z, x0.w, x1.x, x1.y, x1.z, x1.w};
            float bv[8] = {y0.x, y0.y, y0.z, y0.w, y1.x, y1.y, y1.z, y1.w};
            #pragma unroll
            for (int i = 0; i < 8; ++i)
                #pragma unroll
                for (int j = 0; j < 8; ++j)
                    acc[i][j] += av[i] * bv[j];
        }
    }

    #pragma unroll
    for (int i = 0; i < 8; ++i) {
        h8 vh, vl;
        #pragma unroll
        for (int j = 0; j < 8; ++j) {
            float v = acc[i][j] + bias[bn + tx + j];
            _Float16 hh = (_Float16)v;
            vh[j] = hh;
            vl[j] = (_Float16)(v - (float)hh);
        }
        size_t ro = (size_t)(bm + ty + i) * ldy + bn + tx;
        *(h8*)(yhi + ro) = vh;
        *(h8*)(ylo + ro) = vl;
    }
}

// ---------------------------------------------------------------------------
// Small-M split-f16 MFMA GEMM, K=1024 (dfc1/dfc2): 64x64 block, 4 waves,
// wave = 1 m-frag x 4 n-frags, B double-buffered in regs. Grid (N/64, M/64).
// ---------------------------------------------------------------------------
__global__ __launch_bounds__(256, 2) void gemm_mfma_s(
    const _Float16* __restrict__ Ahi, const _Float16* __restrict__ Alo, long long lda,
    const _Float16* __restrict__ wf, const float* __restrict__ bias,
    _Float16* __restrict__ yhi, _Float16* __restrict__ ylo, long long ldy)
{
    __shared__ _Float16 lds[2][64 * 40];
    const int bn   = blockIdx.x << 6;
    const int bm   = blockIdx.y << 6;
    const int tid  = threadIdx.x;
    const int lane = tid & 63, wv = tid >> 6;
    const int l15  = lane & 15, quad = lane >> 4;
    const int r    = tid >> 2, kq = (tid & 3) << 3;

    f32x4 acc[4];
    #pragma unroll
    for (int nf = 0; nf < 4; ++nf) acc[nf] = (f32x4){0.f, 0.f, 0.f, 0.f};

    h8 pAh, pAl;
    h8 BhA[4], BlA[4], BhB[4], BlB[4];
    {
        size_t off = (size_t)(bm + r) * lda + kq;
        pAh = *(const h8*)(Ahi + off);
        pAl = *(const h8*)(Alo + off);
        #pragma unroll
        for (int nf = 0; nf < 4; ++nf) {
            const _Float16* bp = wf + ((size_t)(((bn >> 4) + nf) * 32) * 2) * 512 + lane * 8;
            BhA[nf] = *(const h8*)bp;
            BlA[nf] = *(const h8*)(bp + 512);
        }
    }

#define GS_SI(SI, BHU, BLU, BHF, BLF)                                          \
    {                                                                          \
        __syncthreads();                                                       \
        *(h8*)(&lds[0][r * 40 + kq]) = pAh;                                    \
        *(h8*)(&lds[1][r * 40 + kq]) = pAl;                                    \
        __syncthreads();                                                       \
        {                                                                      \
            int sn = ((SI) + 1 < 32) ? (SI) + 1 : (SI);                        \
            size_t off = (size_t)(bm + r) * lda + (sn << 5) + kq;              \
            pAh = *(const h8*)(Ahi + off);                                     \
            pAl = *(const h8*)(Alo + off);                                     \
            _Pragma("unroll")                                                  \
            for (int nf = 0; nf < 4; ++nf) {                                   \
                const _Float16* bp = wf +                                      \
                    ((size_t)(((bn >> 4) + nf) * 32 + sn) * 2) * 512 + lane * 8;\
                BHF[nf] = *(const h8*)bp;                                      \
                BLF[nf] = *(const h8*)(bp + 512);                              \
            }                                                                  \
        }                                                                      \
        int row = (wv << 4) + l15;                                             \
        h8 axh = *(const h8*)(&lds[0][row * 40 + quad * 8]);                   \
        h8 axl = *(const h8*)(&lds[1][row * 40 + quad * 8]);                   \
        _Pragma("unroll")                                                      \
        for (int nf = 0; nf < 4; ++nf) {                                       \
            acc[nf] = MFMA16(axh, BHU[nf], acc[nf]);                           \
            acc[nf] = MFMA16(axh, BLU[nf], acc[nf]);                           \
            acc[nf] = MFMA16(axl, BHU[nf], acc[nf]);                           \
        }                                                                      \
    }

    for (int si = 0; si < 32; si += 2) {
        GS_SI(si,     BhA, BlA, BhB, BlB);
        GS_SI(si + 1, BhB, BlB, BhA, BlA);
    }
#undef GS_SI

    #pragma unroll
    for (int nf = 0; nf < 4; ++nf) {
        int col = bn + nf * 16 + l15;
        float bv = bias[col];
        #pragma unroll
        for (int rr = 0; rr < 4; ++rr) {
            int m = bm + (wv << 4) + (quad << 2) + rr;
            float v = acc[nf][rr] + bv;
            size_t ro = (size_t)m * ldy + col;
            _Float16 hh = (_Float16)v;
            yhi[ro] = hh;
            ylo[ro] = (_Float16)(v - (float)hh);
        }
    }
}

// ---------------------------------------------------------------------------
// 128x128 split-f16 MFMA GEMM, K=1024 (efc2/efc3/dfc3). 4 waves in 2x2 grid,
// wave = 64x64 (4 m-frags x 4 n-frags). A staged in LDS (k64/super-iter,
// register prefetch); B direct from frag layout, register double-buffered.
// Grid (N/128, M/128). Output fp32 or hi/lo planes.
// ---------------------------------------------------------------------------
__global__ __launch_bounds__(256, 1) void mm128_fc(
    const _Float16* __restrict__ Ahi, const _Float16* __restrict__ Alo, long long lda,
    const _Float16* __restrict__ wf, const float* __restrict__ bias,
    float* __restrict__ Y, long long ldy,
    _Float16* __restrict__ yhi, _Float16* __restrict__ ylo)
{
    __shared__ _Float16 lds[2][128 * 72];
    const int bn   = blockIdx.x << 7;
    const int bm   = blockIdx.y << 7;
    const int tid  = threadIdx.x;
    const int lane = tid & 63, wv = tid >> 6;
    const int wm   = wv >> 1, wn = wv & 1;
    const int l15  = lane & 15, quad = lane >> 4;
    const int r    = tid >> 1, kh = (tid & 1) << 5;   // row, elem offset (0/32)
    const int gbb  = (bn >> 4) + (wn << 2);

    f32x4 acc[4][4];
    #pragma unroll
    for (int mi = 0; mi < 4; ++mi)
        #pragma unroll
        for (int nf = 0; nf < 4; ++nf) acc[mi][nf] = (f32x4){0.f, 0.f, 0.f, 0.f};

    h8 pA[8];
    h8 BhA[8], BlA[8], BhB[8], BlB[8];
    {
        size_t off = (size_t)(bm + r) * lda + kh;
        #pragma unroll
        for (int j = 0; j < 4; ++j) {
            pA[j]     = *(const h8*)(Ahi + off + j * 8);
            pA[4 + j] = *(const h8*)(Alo + off + j * 8);
        }
        #pragma unroll
        for (int s = 0; s < 2; ++s)
            #pragma unroll
            for (int nf = 0; nf < 4; ++nf) {
                const _Float16* bp = wf + ((size_t)((gbb + nf) * 32 + s) * 2) * 512 + lane * 8;
                BhA[s * 4 + nf] = *(const h8*)bp;
                BlA[s * 4 + nf] = *(const h8*)(bp + 512);
            }
    }

#define F_SI(SI, BHU, BLU, BHF, BLF)                                           \
    {                                                                          \
        __syncthreads();                                                       \
        _Pragma("unroll")                                                      \
        for (int j = 0; j < 4; ++j) {                                          \
            *(h8*)(&lds[0][r * 72 + kh + j * 8]) = pA[j];                      \
            *(h8*)(&lds[1][r * 72 + kh + j * 8]) = pA[4 + j];                  \
        }                                                                      \
        __syncthreads();                                                       \
        {                                                                      \
            int sn = ((SI) + 1 < 16) ? (SI) + 1 : (SI);                        \
            size_t off = (size_t)(bm + r) * lda + (sn << 6) + kh;              \
            _Pragma("unroll")                                                  \
            for (int j = 0; j < 4; ++j) {                                      \
                pA[j]     = *(const h8*)(Ahi + off + j * 8);                   \
                pA[4 + j] = *(const h8*)(Alo + off + j * 8);                   \
            }                                                                  \
            int ksb = sn << 1;                                                 \
            _Pragma("unroll")                                                  \
            for (int s = 0; s < 2; ++s)                                        \
                _Pragma("unroll")                                              \
                for (int nf = 0; nf < 4; ++nf) {                               \
                    const _Float16* bp = wf +                                  \
                        ((size_t)((gbb + nf) * 32 + ksb + s) * 2) * 512 + lane * 8; \
                    BHF[s * 4 + nf] = *(const h8*)bp;                          \
                    BLF[s * 4 + nf] = *(const h8*)(bp + 512);                  \
                }                                                              \
        }                                                                      \
        _Pragma("unroll")                                                      \
        for (int s = 0; s < 2; ++s) {                                          \
            h8 axh[4], axl[4];                                                 \
            _Pragma("unroll")                                                  \
            for (int mi = 0; mi < 4; ++mi) {                                   \
                int row = (wm << 6) + (mi << 4) + l15;                         \
                axh[mi] = *(const h8*)(&lds[0][row * 72 + s * 32 + quad * 8]); \
                axl[mi] = *(const h8*)(&lds[1][row * 72 + s * 32 + quad * 8]); \
            }                                                                  \
            _Pragma("unroll")                                                  \
            for (int nf = 0; nf < 4; ++nf)                                     \
                _Pragma("unroll")                                              \
                for (int mi = 0; mi < 4; ++mi) {                               \
                    acc[mi][nf] = MFMA16(axh[mi], BHU[s * 4 + nf], acc[mi][nf]); \
                    acc[mi][nf] = MFMA16(axh[mi], BLU[s * 4 + nf], acc[mi][nf]); \
                    acc[mi][nf] = MFMA16(axl[mi], BHU[s * 4 + nf], acc[mi][nf]); \
                }                                                              \
        }                                                                      \
    }

    for (int si = 0; si < 16; si += 2) {
        F_SI(si,     BhA, BlA, BhB, BlB);
        F_SI(si + 1, BhB, BlB, BhA, BlA);
    }
#undef F_SI

    #pragma unroll
    for (int nf = 0; nf < 4; ++nf) {
        int col = bn + (wn << 6) + (nf << 4) + l15;
        float bv = bias[col];
        #pragma unroll
        for (int mi = 0; mi < 4; ++mi) {
            #pragma unroll
            for (int rr = 0; rr < 4; ++rr) {
                int m = bm + (wm << 6) + (mi << 4) + (quad << 2) + rr;
                float v = acc[mi][nf][rr] + bv;
                size_t ro = (size_t)m * ldy + col;
                if (yhi) {
                    _Float16 hh = (_Float16)v;
                    yhi[ro] = hh;
                    ylo[ro] = (_Float16)(v - (float)hh);
                } else {
                    Y[ro] = v;
                }
            }
        }
    }
}

// ---------------------------------------------------------------------------
// Fused split-f16 MFMA LSTM step, 128x128 block, 2x2 wave grid.
// lin bits: [z | jt4..3 | bt | jt2..0]; bt toggles bit3 -> co-XCD pairs.
// Encoder grid 128 (z in {0,1}: wavefront fusion); decoder grid 64 (z=0).
// Block: 128 batch (bt) x (32 j x 4 gates); wave: 64 batch x (16 j x 4 gates);
// n-frag nf = gate (gb = nf*64 + jg, jg = jt*2 + wn) -> all gates in-lane.
// ---------------------------------------------------------------------------
struct LstmSet {
    const _Float16 *xhi, *xlo; long long ldx;
    const _Float16 *hphi, *hplo;
    const _Float16 *wf;
    const float *bih, *bhh;
    float *c;
    _Float16 *hohi, *holo;
};

__global__ __launch_bounds__(256, 1) void lstm_mfma5(LstmSet s0, LstmSet s1)
{
    const int lin = blockIdx.x;
    const int jt  = (lin & 7) | (((lin >> 4) & 3) << 3);
    const int bt  = (lin >> 3) & 1;
    LstmSet s = (lin >> 6) ? s1 : s0;
    if (s.wf == nullptr) return;
    __shared__ _Float16 lds[2][128 * 72];
    const int tid  = threadIdx.x;
    const int bm   = bt << 7;
    const int lane = tid & 63, wv = tid >> 6;
    const int wm   = wv >> 1, wn = wv & 1;
    const int l15  = lane & 15, quad = lane >> 4;
    const int r    = tid >> 1, kh = (tid & 1) << 5;
    const int jg   = (jt << 1) + wn;

    f32x4 acc[4][4];
    #pragma unroll
    for (int mi = 0; mi < 4; ++mi)
        #pragma unroll
        for (int nf = 0; nf < 4; ++nf) acc[mi][nf] = (f32x4){0.f, 0.f, 0.f, 0.f};

    h8 pA[8];
    h8 BhA[8], BlA[8], BhB[8], BlB[8];
    {
        size_t off = (size_t)(bm + r) * s.ldx + kh;
        #pragma unroll
        for (int j = 0; j < 4; ++j) {
            pA[j]     = *(const h8*)(s.xhi + off + j * 8);
            pA[4 + j] = *(const h8*)(s.xlo + off + j * 8);
        }
        #pragma unroll
        for (int ss = 0; ss < 2; ++ss)
            #pragma unroll
            for (int nf = 0; nf < 4; ++nf) {
                const _Float16* bp = s.wf +
                    ((size_t)((nf * 64 + jg) * 32 + ss) * 2) * 512 + lane * 8;
                BhA[ss * 4 + nf] = *(const h8*)bp;
                BlA[ss * 4 + nf] = *(const h8*)(bp + 512);
            }
    }

#define L5_SI(SI, BHU, BLU, BHF, BLF)                                          \
    {                                                                          \
        __syncthreads();                                                       \
        _Pragma("unroll")                                                      \
        for (int j = 0; j < 4; ++j) {                                          \
            *(h8*)(&lds[0][r * 72 + kh + j * 8]) = pA[j];                      \
            *(h8*)(&lds[1][r * 72 + kh + j * 8]) = pA[4 + j];                  \
        }                                                                      \
        __syncthreads();                                                       \
        {                                                                      \
            int sn  = ((SI) + 1 < 32) ? (SI) + 1 : (SI);                       \
            int phx = sn >> 4;                                                 \
            const _Float16* xh = phx ? s.hphi : s.xhi;                         \
            const _Float16* xl = phx ? s.hplo : s.xlo;                         \
            long long ld = phx ? Hn : s.ldx;                                   \
            size_t off = (size_t)(bm + r) * ld + ((sn & 15) << 6) + kh;        \
            _Pragma("unroll")                                                  \
            for (int j = 0; j < 4; ++j) {                                      \
                pA[j]     = *(const h8*)(xh + off + j * 8);                    \
                pA[4 + j] = *(const h8*)(xl + off + j * 8);                    \
            }                                                                  \
            const _Float16* wb = s.wf + (size_t)(sn >> 4) * WFRAG_4096;        \
            int ksb = (sn & 15) << 1;                                          \
            _Pragma("unroll")                                                  \
            for (int ss = 0; ss < 2; ++ss)                                     \
                _Pragma("unroll")                                              \
                for (int nf = 0; nf < 4; ++nf) {                               \
                    const _Float16* bp = wb +                                  \
                        ((size_t)((nf * 64 + jg) * 32 + ksb + ss) * 2) * 512   \
                        + lane * 8;                                            \
                    BHF[ss * 4 + nf] = *(const h8*)bp;                         \
                    BLF[ss * 4 + nf] = *(const h8*)(bp + 512);                 \
                }                                                              \
        }                                                                      \
        _Pragma("unroll")                                                      \
        for (int ss = 0; ss < 2; ++ss) {                                       \
            h8 axh[4], axl[4];                                                 \
            _Pragma("unroll")                                                  \
            for (int mi = 0; mi < 4; ++mi) {                                   \
                int row = (wm << 6) + (mi << 4) + l15;                         \
                axh[mi] = *(const h8*)(&lds[0][row * 72 + ss * 32 + quad * 8]);\
                axl[mi] = *(const h8*)(&lds[1][row * 72 + ss * 32 + quad * 8]);\
            }                                                                  \
            _Pragma("unroll")                                                  \
            for (int nf = 0; nf < 4; ++nf)                                     \
                _Pragma("unroll")                                              \
                for (int mi = 0; mi < 4; ++mi) {                               \
                    acc[mi][nf] = MFMA16(axh[mi], BHU[ss * 4 + nf], acc[mi][nf]); \
                    acc[mi][nf] = MFMA16(axh[mi], BLU[ss * 4 + nf], acc[mi][nf]); \
                    acc[mi][nf] = MFMA16(axl[mi], BHU[ss * 4 + nf], acc[mi][nf]); \
                }                                                              \
        }                                                                      \
    }

    for (int si = 0; si < 32; si += 2) {
        L5_SI(si,     BhA, BlA, BhB, BlB);
        L5_SI(si + 1, BhB, BlB, BhA, BlA);
    }
#undef L5_SI

    // Epilogue: lane holds all 4 gates (nf) for 4x4 batch rows x col j.
    float bs[4];
    #pragma unroll
    for (int nf = 0; nf < 4; ++nf) {
        int br = nf * Hn + (jg << 4) + l15;
        bs[nf] = s.bih[br] + s.bhh[br];
    }
    #pragma unroll
    for (int mi = 0; mi < 4; ++mi) {
        #pragma unroll
        for (int rr = 0; rr < 4; ++rr) {
            int m = (wm << 6) + (mi << 4) + (quad << 2) + rr;
            size_t idx = (size_t)(bm + m) * Hn + (jg << 4) + l15;
            float gi = acc[mi][0][rr] + bs[0];
            float gf = acc[mi][1][rr] + bs[1];
            float gg = acc[mi][2][rr] + bs[2];
            float go = acc[mi][3][rr] + bs[3];
            float cv = s.c[idx];
            float si_ = 1.0f / (1.0f + expf(-gi));
            float sf  = 1.0f / (1.0f + expf(-gf));
            float so  = 1.0f / (1.0f + expf(-go));
            float cn = sf * cv + si_ * tanhf(gg);
            float hn = so * tanhf(cn);
            s.c[idx] = cn;
            _Float16 hh = (_Float16)hn;
            s.hohi[idx] = hh;
            s.holo[idx] = (_Float16)(hn - (float)hh);
        }
    }
}

// ---------------------------------------------------------------------------
// Per-row top-k over V=16384; decoded indices + next-step embedding planes.
// ---------------------------------------------------------------------------
__global__ __launch_bounds__(256) void beam_kernel(
    const float* __restrict__ scores, float* __restrict__ decoded,
    _Float16* __restrict__ embhi, _Float16* __restrict__ emblo,
    const float* __restrict__ fqw_w, const float* __restrict__ fqw_b,
    const float* __restrict__ fql_w, const float* __restrict__ fql_b,
    int step, int kcur)
{
    __shared__ float svals[256];
    __shared__ int   sidx[256];
    __shared__ int   sel[Kn];
    const int b   = blockIdx.x;
    const int tid = threadIdx.x;
    const float* row = scores + (size_t)b * Vn;

    for (int rr = 0; rr < kcur; ++rr) {
        float best = -INFINITY;
        int   bidx = Vn;
        for (int i = tid; i < Vn; i += 256) {
            bool skip = false;
            for (int q = 0; q < rr; ++q) if (sel[q] == i) skip = true;
            float v = row[i];
            if (!skip && v > best) { best = v; bidx = i; }
        }
        svals[tid] = best; sidx[tid] = bidx;
        __syncthreads();
        for (int s = 128; s > 0; s >>= 1) {
            if (tid < s) {
                float v2 = svals[tid + s]; int i2 = sidx[tid + s];
                if (v2 > svals[tid] || (v2 == svals[tid] && i2 < sidx[tid])) {
                    svals[tid] = v2; sidx[tid] = i2;
                }
            }
            __syncthreads();
        }
        if (tid == 0) sel[rr] = sidx[0];
        __syncthreads();
    }

    if (tid < kcur) {
        int s_ = sel[tid];
        int fw = s_ / QLn, fl = s_ % QLn;
        float* dp = decoded + ((size_t)(b * DELTAn + step) * Kn + tid) * 2;
        dp[0] = (float)fl;
        dp[1] = (float)fw;
    }

    const int fw0 = sel[0] / QLn;
    const int fl0 = sel[0] % QLn;
    for (int o = tid; o < 512; o += 256) {
        float v0 = fqw_w[o * QLn + fw0] + fqw_b[o];
        float v1 = fql_w[o * QLn + fl0] + fql_b[o];
        _Float16 h0 = (_Float16)v0;
        _Float16 h1 = (_Float16)v1;
        size_t i0 = (size_t)b * Hn + o;
        embhi[i0]       = h0; emblo[i0]       = (_Float16)(v0 - (float)h0);
        embhi[i0 + 512] = h1; emblo[i0 + 512] = (_Float16)(v1 - (float)h1);
    }
}

// ---------------------------------------------------------------------------
extern "C" void kernel_launch(void* const* d_in, const int* in_sizes, int n_in,
                              void* d_out, int out_size, void* d_ws, size_t ws_size,
                              hipStream_t stream)
{
    int ii = 0;
    const float* x       = (const float*)d_in[ii++];
    const float* efc1_w  = (const float*)d_in[ii++];
    const float* efc1_b  = (const float*)d_in[ii++];
    const float* efc2_w  = (const float*)d_in[ii++];
    const float* efc2_b  = (const float*)d_in[ii++];
    const float* efc3_w  = (const float*)d_in[ii++];
    const float* efc3_b  = (const float*)d_in[ii++];
    const float* el1_wih = (const float*)d_in[ii++];
    const float* el1_whh = (const float*)d_in[ii++];
    const float* el1_bih = (const float*)d_in[ii++];
    const float* el1_bhh = (const float*)d_in[ii++];
    const float* el2_wih = (const float*)d_in[ii++];
    const float* el2_whh = (const float*)d_in[ii++];
    const float* el2_bih = (const float*)d_in[ii++];
    const float* el2_bhh = (const float*)d_in[ii++];
    const float* dl1_wih = (const float*)d_in[ii++];
    const float* dl1_whh = (const float*)d_in[ii++];
    const float* dl1_bih = (const float*)d_in[ii++];
    const float* dl1_bhh = (const float*)d_in[ii++];
    const float* dl2_wih = (const float*)d_in[ii++];
    const float* dl2_whh = (const float*)d_in[ii++];
    const float* dl2_bih = (const float*)d_in[ii++];
    const float* dl2_bhh = (const float*)d_in[ii++];
    const float* dfc1_w  = (const float*)d_in[ii++];
    const float* dfc1_b  = (const float*)d_in[ii++];
    const float* dfc2_w  = (const float*)d_in[ii++];
    const float* dfc2_b  = (const float*)d_in[ii++];
    const float* dfc3_w  = (const float*)d_in[ii++];
    const float* dfc3_b  = (const float*)d_in[ii++];
    const float* fqw_w   = (const float*)d_in[ii++];
    const float* fqw_b   = (const float*)d_in[ii++];
    const float* fql_w   = (const float*)d_in[ii++];
    const float* fql_b   = (const float*)d_in[ii++];

    float* out = (float*)d_out;

    // ---- Workspace layout (~245 MB) ----
    char* p = (char*)d_ws;
    auto alloc = [&](size_t bytes) { char* q = p; p += (bytes + 255) & ~(size_t)255; return q; };
    _Float16* bufhi = (_Float16*)alloc((size_t)32768 * 1024 * 2);  // e3 hi; later dfc3' frags
    _Float16* buflo = (_Float16*)alloc((size_t)32768 * 1024 * 2);  // e3 lo (dfc3' spillover)
    _Float16* slot0 = (_Float16*)alloc((size_t)2 * WFRAG_4096 * 2); // l1 frags
    _Float16* slot1 = (_Float16*)alloc((size_t)2 * WFRAG_4096 * 2); // l2 frags
    _Float16* efw2  = (_Float16*)alloc((size_t)2097152 * 2);        // efc2' frags
    _Float16* efw3  = (_Float16*)alloc((size_t)2097152 * 2);        // efc3' frags
    _Float16* dfw1  = (_Float16*)alloc((size_t)2097152 * 2);        // dfc1' frags
    _Float16* dfw2  = (_Float16*)alloc((size_t)2097152 * 2);        // dfc2' frags
    float*    scores= (float*)alloc((size_t)256 * Vn * 4);          // fp32; t1 planes in FC
    char*  zbase = p;                                               // zero block:
    float* c1    = (float*)alloc((size_t)256 * Hn * 4);
    float* c2    = (float*)alloc((size_t)256 * Hn * 4);
    _Float16* h1hiA = (_Float16*)alloc((size_t)256 * Hn * 2);
    _Float16* h1loA = (_Float16*)alloc((size_t)256 * Hn * 2);
    _Float16* h2hiA = (_Float16*)alloc((size_t)256 * Hn * 2);
    _Float16* h2loA = (_Float16*)alloc((size_t)256 * Hn * 2);
    size_t zbytes = (size_t)(p - zbase);
    _Float16* h1hiB = (_Float16*)alloc((size_t)256 * Hn * 2);
    _Float16* h1loB = (_Float16*)alloc((size_t)256 * Hn * 2);
    _Float16* h2hiB = (_Float16*)alloc((size_t)256 * Hn * 2);
    _Float16* h2loB = (_Float16*)alloc((size_t)256 * Hn * 2);
    _Float16* f1hi  = (_Float16*)alloc((size_t)256 * Hn * 2);
    _Float16* f1lo  = (_Float16*)alloc((size_t)256 * Hn * 2);
    _Float16* f2hi  = (_Float16*)alloc((size_t)256 * Hn * 2);
    _Float16* f2lo  = (_Float16*)alloc((size_t)256 * Hn * 2);
    _Float16* embhi = (_Float16*)alloc((size_t)256 * Hn * 2);
    _Float16* emblo = (_Float16*)alloc((size_t)256 * Hn * 2);

    // FC-phase temps (regions dead during FC):
    _Float16* t1hi = (_Float16*)scores;            // 4096x1024 planes in scores
    _Float16* t1lo = t1hi + (size_t)4096 * 1024;
    _Float16* t2hi = slot0;                        // 4096x1024 planes in slot0
    _Float16* t2lo = t2hi + (size_t)4096 * 1024;
    _Float16* dfc3f = bufhi;                       // dfc3' frags (67.1 MB: bufhi+3MB of buflo)

    const long long TH = (long long)Tn * Hn;

    // ---- efc2'/efc3' fragment conversion ----
    hipLaunchKernelGGL(wconv_frag, dim3(512), dim3(256), 0, stream, efc2_w, efw2, 64);
    hipLaunchKernelGGL(wconv_frag, dim3(512), dim3(256), 0, stream, efc3_w, efw3, 64);

    // ---- Encoder FC chain, 8 chunks of 4096 rows ----
    for (int c = 0; c < 8; ++c) {
        const float* xc = x + (size_t)c * 4096 * 64;
        size_t ofs = (size_t)c * 4096 * 1024;
        hipLaunchKernelGGL(gemm_nt_128, dim3(8, 32), dim3(256), 0, stream,
                           xc, 64, efc1_w, 64, efc1_b, t1hi, t1lo, Hn);
        hipLaunchKernelGGL(mm128_fc, dim3(8, 32), dim3(256), 0, stream,
                           t1hi, t1lo, (long long)Hn, efw2, efc2_b,
                           (float*)nullptr, (long long)Hn, t2hi, t2lo);
        hipLaunchKernelGGL(mm128_fc, dim3(8, 32), dim3(256), 0, stream,
                           t2hi, t2lo, (long long)Hn, efw3, efc3_b,
                           (float*)nullptr, (long long)Hn, bufhi + ofs, buflo + ofs);
    }

    // ---- Encoder LSTM weight frags ----
    hipLaunchKernelGGL(wconv_frag, dim3(2048), dim3(256), 0, stream, el1_wih, slot0, 256);
    hipLaunchKernelGGL(wconv_frag, dim3(2048), dim3(256), 0, stream, el1_whh, slot0 + WFRAG_4096, 256);
    hipLaunchKernelGGL(wconv_frag, dim3(2048), dim3(256), 0, stream, el2_wih, slot1, 256);
    hipLaunchKernelGGL(wconv_frag, dim3(2048), dim3(256), 0, stream, el2_whh, slot1 + WFRAG_4096, 256);

    hipMemsetAsync(zbase, 0, zbytes, stream);

    // ---- Encoder LSTMs: wavefront-fused l1(t=d) + l2(t=d-1), grid 128 ----
    _Float16 *h1hiC = h1hiA, *h1loC = h1loA, *h1hiN = h1hiB, *h1loN = h1loB;
    _Float16 *h2hiC = h2hiA, *h2loC = h2loA, *h2hiN = h2hiB, *h2loN = h2loB;
    _Float16* tp;
    for (int d = 0; d <= Tn; ++d) {
        LstmSet s0 = {}, s1 = {};
        if (d < Tn) {
            s0.xhi = bufhi + (size_t)d * Hn; s0.xlo = buflo + (size_t)d * Hn; s0.ldx = TH;
            s0.hphi = h1hiC; s0.hplo = h1loC; s0.wf = slot0;
            s0.bih = el1_bih; s0.bhh = el1_bhh; s0.c = c1;
            s0.hohi = h1hiN; s0.holo = h1loN;
        }
        if (d >= 1) {
            s1.xhi = h1hiC; s1.xlo = h1loC; s1.ldx = Hn;
            s1.hphi = h2hiC; s1.hplo = h2loC; s1.wf = slot1;
            s1.bih = el2_bih; s1.bhh = el2_bhh; s1.c = c2;
            s1.hohi = h2hiN; s1.holo = h2loN;
        }
        hipLaunchKernelGGL(lstm_mfma5, dim3(128), dim3(256), 0, stream, s0, s1);
        if (d < Tn)  { tp = h1hiC; h1hiC = h1hiN; h1hiN = tp;
                       tp = h1loC; h1loC = h1loN; h1loN = tp; }
        if (d >= 1)  { tp = h2hiC; h2hiC = h2hiN; h2hiN = tp;
                       tp = h2loC; h2loC = h2loN; h2loN = tp; }
    }

    // ---- Decoder weight frags ----
    hipLaunchKernelGGL(wconv_frag, dim3(2048), dim3(256), 0, stream, dl1_wih, slot0, 256);
    hipLaunchKernelGGL(wconv_frag, dim3(2048), dim3(256), 0, stream, dl1_whh, slot0 + WFRAG_4096, 256);
    hipLaunchKernelGGL(wconv_frag, dim3(2048), dim3(256), 0, stream, dl2_wih, slot1, 256);
    hipLaunchKernelGGL(wconv_frag, dim3(2048), dim3(256), 0, stream, dl2_whh, slot1 + WFRAG_4096, 256);
    hipLaunchKernelGGL(wconv_frag, dim3(8192), dim3(256), 0, stream, dfc3_w, dfc3f, 1024);
    hipLaunchKernelGGL(wconv_frag, dim3(512), dim3(256), 0, stream, dfc1_w, dfw1, 64);
    hipLaunchKernelGGL(wconv_frag, dim3(512), dim3(256), 0, stream, dfc2_w, dfw2, 64);

    hipMemsetAsync(out, 0, (size_t)out_size * sizeof(float), stream);

    // ---- Decoder: 16 autoregressive steps ----
    for (int it = 0; it < DELTAn; ++it) {
        LstmSet s0 = {}, sx = {};
        s0.xhi = (it == 0) ? h2hiC : embhi;
        s0.xlo = (it == 0) ? h2loC : emblo;
        s0.ldx = Hn;
        s0.hphi = h1hiC; s0.hplo = h1loC; s0.wf = slot0;
        s0.bih = dl1_bih; s0.bhh = dl1_bhh; s0.c = c1;
        s0.hohi = h1hiN; s0.holo = h1loN;
        hipLaunchKernelGGL(lstm_mfma5, dim3(64), dim3(256), 0, stream, s0, sx);
        tp = h1hiC; h1hiC = h1hiN; h1hiN = tp;
        tp = h1loC; h1loC = h1loN; h1loN = tp;

        LstmSet s2 = {};
        s2.xhi = h1hiC; s2.xlo = h1loC; s2.ldx = Hn;
        s2.hphi = h2hiC; s2.hplo = h2loC; s2.wf = slot1;
        s2.bih = dl2_bih; s2.bhh = dl2_bhh; s2.c = c2;
        s2.hohi = h2hiN; s2.holo = h2loN;
        hipLaunchKernelGGL(lstm_mfma5, dim3(64), dim3(256), 0, stream, s2, sx);
        tp = h2hiC; h2hiC = h2hiN; h2hiN = tp;
        tp = h2loC; h2loC = h2loN; h2loN = tp;

        // Decoder FC chain (split-f16 MFMA, plane dataflow)
        hipLaunchKernelGGL(gemm_mfma_s, dim3(16, 4), dim3(256), 0, stream,
                           h2hiC, h2loC, (long long)Hn, dfw1, dfc1_b,
                           f1hi, f1lo, (long long)Hn);
        hipLaunchKernelGGL(gemm_mfma_s, dim3(16, 4), dim3(256), 0, stream,
                           f1hi, f1lo, (long long)Hn, dfw2, dfc2_b,
                           f2hi, f2lo, (long long)Hn);
        hipLaunchKernelGGL(mm128_fc, dim3(128, 2), dim3(256), 0, stream,
                           f2hi, f2lo, (long long)Hn, dfc3f, dfc3_b,
                           scores, (long long)Vn, (_Float16*)nullptr, (_Float16*)nullptr);
        hipLaunchKernelGGL(beam_kernel, dim3(Bn), dim3(256), 0, stream,
                           scores, out, embhi, emblo, fqw_w, fqw_b, fql_w, fql_b,
                           it, (it == 0) ? Kn : 1);
    }
}

// Round 9
// 9072.651 us; speedup vs baseline: 1.4792x; 1.4792x over previous
//
#include <hip/hip_runtime.h>
#include <math.h>

// Problem constants
#define Hn     1024
#define Bn     256
#define Tn     128
#define Vn     16384
#define DELTAn 16
#define Kn     5
#define QLn    128

typedef _Float16 h8 __attribute__((ext_vector_type(8)));
typedef _Float16 h4 __attribute__((ext_vector_type(4)));
typedef float    f32x4 __attribute__((ext_vector_type(4)));

#define MFMA16(a, b, c) __builtin_amdgcn_mfma_f32_16x16x32_f16(a, b, c, 0, 0, 0)

// Per-matrix fragment region size (N=4096, K=1024)
#define WFRAG_4096 8388608

// ---------------------------------------------------------------------------
// Fragment-shuffle weight conversion: W (N x 1024 fp32, row-major) ->
// chunk (gb, ks) = 64 lanes x 8 f16, hi plane then lo plane.
// lane l holds W[gb*16 + (l&15)][ks*32 + (l>>4)*8 + j], j=0..7.
// ---------------------------------------------------------------------------
__global__ __launch_bounds__(256) void wconv_frag(
    const float* __restrict__ W, _Float16* __restrict__ wf, int ngb)
{
    int wid  = (blockIdx.x * 256 + threadIdx.x) >> 6;
    int lane = threadIdx.x & 63;
    int gb = wid >> 5, ks = wid & 31;
    if (gb >= ngb) return;
    const float* src = W + (size_t)(gb * 16 + (lane & 15)) * 1024 + ks * 32 + (lane >> 4) * 8;
    float4 v0 = *(const float4*)src;
    float4 v1 = *(const float4*)(src + 4);
    float vv[8] = {v0.x, v0.y, v0.z, v0.w, v1.x, v1.y, v1.z, v1.w};
    h8 vh, vl;
    #pragma unroll
    for (int j = 0; j < 8; ++j) {
        _Float16 hh = (_Float16)vv[j];
        vh[j] = hh;
        vl[j] = (_Float16)(vv[j] - (float)hh);
    }
    _Float16* dst = wf + ((size_t)(gb * 32 + ks) * 2) * 512 + lane * 8;
    *(h8*)dst        = vh;
    *(h8*)(dst + 512) = vl;
}

// ---------------------------------------------------------------------------
// Big-tile fp32 GEMM (efc1 only, K=64): 128x128 tile, 8x8 microtile.
// ---------------------------------------------------------------------------
__global__ __launch_bounds__(256) void gemm_nt_128(
    const float* __restrict__ A, int lda, const float* __restrict__ W, int K,
    const float* __restrict__ bias, _Float16* __restrict__ yhi,
    _Float16* __restrict__ ylo, int ldy)
{
    __shared__ float As[16 * 132];
    __shared__ float Bs[16 * 132];
    const int bm   = blockIdx.y << 7;
    const int bn   = blockIdx.x << 7;
    const int tid  = threadIdx.x;
    const int tx   = (tid & 15) << 3;
    const int ty   = (tid >> 4) << 3;
    const int lrow = tid >> 1;
    const int lk   = (tid & 1) << 3;

    float acc[8][8] = {};
    const float* arow = A + (size_t)(bm + lrow) * lda + lk;
    const float* brow = W + (size_t)(bn + lrow) * K   + lk;

    for (int kt = 0; kt < K; kt += 16) {
        float4 a0 = *(const float4*)(arow + kt);
        float4 a1 = *(const float4*)(arow + kt + 4);
        float4 b0 = *(const float4*)(brow + kt);
        float4 b1 = *(const float4*)(brow + kt + 4);
        __syncthreads();
        As[(lk + 0) * 132 + lrow] = a0.x; As[(lk + 1) * 132 + lrow] = a0.y;
        As[(lk + 2) * 132 + lrow] = a0.z; As[(lk + 3) * 132 + lrow] = a0.w;
        As[(lk + 4) * 132 + lrow] = a1.x; As[(lk + 5) * 132 + lrow] = a1.y;
        As[(lk + 6) * 132 + lrow] = a1.z; As[(lk + 7) * 132 + lrow] = a1.w;
        Bs[(lk + 0) * 132 + lrow] = b0.x; Bs[(lk + 1) * 132 + lrow] = b0.y;
        Bs[(lk + 2) * 132 + lrow] = b0.z; Bs[(lk + 3) * 132 + lrow] = b0.w;
        Bs[(lk + 4) * 132 + lrow] = b1.x; Bs[(lk + 5) * 132 + lrow] = b1.y;
        Bs[(lk + 6) * 132 + lrow] = b1.z; Bs[(lk + 7) * 132 + lrow] = b1.w;
        __syncthreads();
        #pragma unroll
        for (int k = 0; k < 16; ++k) {
            float4 x0 = *(const float4*)(As + k * 132 + ty);
            float4 x1 = *(const float4*)(As + k * 132 + ty + 4);
            float4 y0 = *(const float4*)(Bs + k * 132 + tx);
            float4 y1 = *(const float4*)(Bs + k * 132 + tx + 4);
            float av[8] = {x0.x, x0.y, x0.z, x0.w, x1.x, x1.y, x1.z, x1.w};
            float bv[8] = {y0.x, y0.y, y0.z, y0.w, y1.x, y1.y, y1.z, y1.w};
            #pragma unroll
            for (int i = 0; i < 8; ++i)
                #pragma unroll
                for (int j = 0; j < 8; ++j)
                    acc[i][j] += av[i] * bv[j];
        }
    }

    #pragma unroll
    for (int i = 0; i < 8; ++i) {
        h8 vh, vl;
        #pragma unroll
        for (int j = 0; j < 8; ++j) {
            float v = acc[i][j] + bias[bn + tx + j];
            _Float16 hh = (_Float16)v;
            vh[j] = hh;
            vl[j] = (_Float16)(v - (float)hh);
        }
        size_t ro = (size_t)(bm + ty + i) * ldy + bn + tx;
        *(h8*)(yhi + ro) = vh;
        *(h8*)(ylo + ro) = vl;
    }
}

// ---------------------------------------------------------------------------
// Small-M split-f16 MFMA GEMM, K=1024 (dfc1/dfc2): 64x64 block, 4 waves,
// wave = 1 m-frag x 4 n-frags, B double-buffered in regs. Grid (N/64, M/64).
// ---------------------------------------------------------------------------
__global__ __launch_bounds__(256, 2) void gemm_mfma_s(
    const _Float16* __restrict__ Ahi, const _Float16* __restrict__ Alo, long long lda,
    const _Float16* __restrict__ wf, const float* __restrict__ bias,
    _Float16* __restrict__ yhi, _Float16* __restrict__ ylo, long long ldy)
{
    __shared__ _Float16 lds[2][64 * 40];
    const int bn   = blockIdx.x << 6;
    const int bm   = blockIdx.y << 6;
    const int tid  = threadIdx.x;
    const int lane = tid & 63, wv = tid >> 6;
    const int l15  = lane & 15, quad = lane >> 4;
    const int r    = tid >> 2, kq = (tid & 3) << 3;

    f32x4 acc[4];
    #pragma unroll
    for (int nf = 0; nf < 4; ++nf) acc[nf] = (f32x4){0.f, 0.f, 0.f, 0.f};

    h8 pAh, pAl;
    h8 BhA[4], BlA[4], BhB[4], BlB[4];
    {
        size_t off = (size_t)(bm + r) * lda + kq;
        pAh = *(const h8*)(Ahi + off);
        pAl = *(const h8*)(Alo + off);
        #pragma unroll
        for (int nf = 0; nf < 4; ++nf) {
            const _Float16* bp = wf + ((size_t)(((bn >> 4) + nf) * 32) * 2) * 512 + lane * 8;
            BhA[nf] = *(const h8*)bp;
            BlA[nf] = *(const h8*)(bp + 512);
        }
    }

#define GS_SI(SI, BHU, BLU, BHF, BLF)                                          \
    {                                                                          \
        __syncthreads();                                                       \
        *(h8*)(&lds[0][r * 40 + kq]) = pAh;                                    \
        *(h8*)(&lds[1][r * 40 + kq]) = pAl;                                    \
        __syncthreads();                                                       \
        {                                                                      \
            int sn = ((SI) + 1 < 32) ? (SI) + 1 : (SI);                        \
            size_t off = (size_t)(bm + r) * lda + (sn << 5) + kq;              \
            pAh = *(const h8*)(Ahi + off);                                     \
            pAl = *(const h8*)(Alo + off);                                     \
            _Pragma("unroll")                                                  \
            for (int nf = 0; nf < 4; ++nf) {                                   \
                const _Float16* bp = wf +                                      \
                    ((size_t)(((bn >> 4) + nf) * 32 + sn) * 2) * 512 + lane * 8;\
                BHF[nf] = *(const h8*)bp;                                      \
                BLF[nf] = *(const h8*)(bp + 512);                              \
            }                                                                  \
        }                                                                      \
        int row = (wv << 4) + l15;                                             \
        h8 axh = *(const h8*)(&lds[0][row * 40 + quad * 8]);                   \
        h8 axl = *(const h8*)(&lds[1][row * 40 + quad * 8]);                   \
        _Pragma("unroll")                                                      \
        for (int nf = 0; nf < 4; ++nf) {                                       \
            acc[nf] = MFMA16(axh, BHU[nf], acc[nf]);                           \
            acc[nf] = MFMA16(axh, BLU[nf], acc[nf]);                           \
            acc[nf] = MFMA16(axl, BHU[nf], acc[nf]);                           \
        }                                                                      \
    }

    for (int si = 0; si < 32; si += 2) {
        GS_SI(si,     BhA, BlA, BhB, BlB);
        GS_SI(si + 1, BhB, BlB, BhA, BlA);
    }
#undef GS_SI

    #pragma unroll
    for (int nf = 0; nf < 4; ++nf) {
        int col = bn + nf * 16 + l15;
        float bv = bias[col];
        #pragma unroll
        for (int rr = 0; rr < 4; ++rr) {
            int m = bm + (wv << 4) + (quad << 2) + rr;
            float v = acc[nf][rr] + bv;
            size_t ro = (size_t)m * ldy + col;
            _Float16 hh = (_Float16)v;
            yhi[ro] = hh;
            ylo[ro] = (_Float16)(v - (float)hh);
        }
    }
}

// ---------------------------------------------------------------------------
// 64x128 split-f16 MFMA GEMM, K=1024 (efc2/efc3/dfc3). 4 waves in 2(m)x2(n)
// grid; wave = 32 rows (2 m-frags) x 64 cols (4 n-frags). A staged in LDS
// (k64/si, register prefetch); B direct from frag layout, register dbuf.
// Grid (N/128, M/64). m-duplicates of an n-tile land co-XCD automatically
// (lin stride N/128 is a multiple of 8 for all uses). Output fp32 or planes.
// ---------------------------------------------------------------------------
__global__ __launch_bounds__(256, 2) void mm64x128(
    const _Float16* __restrict__ Ahi, const _Float16* __restrict__ Alo, long long lda,
    const _Float16* __restrict__ wf, const float* __restrict__ bias,
    float* __restrict__ Y, long long ldy,
    _Float16* __restrict__ yhi, _Float16* __restrict__ ylo)
{
    __shared__ _Float16 lds[2][64 * 72];
    const int bn   = blockIdx.x << 7;
    const int bm   = blockIdx.y << 6;
    const int tid  = threadIdx.x;
    const int lane = tid & 63, wv = tid >> 6;
    const int wm   = wv >> 1, wn = wv & 1;
    const int l15  = lane & 15, quad = lane >> 4;
    const int r    = tid >> 2, kh = (tid & 3) << 4;
    const int gbb  = (bn >> 4) + (wn << 2);

    f32x4 acc[2][4];
    #pragma unroll
    for (int mi = 0; mi < 2; ++mi)
        #pragma unroll
        for (int nf = 0; nf < 4; ++nf) acc[mi][nf] = (f32x4){0.f, 0.f, 0.f, 0.f};

    h8 pA[4];
    h8 BhA[8], BlA[8], BhB[8], BlB[8];
    {
        size_t off = (size_t)(bm + r) * lda + kh;
        pA[0] = *(const h8*)(Ahi + off); pA[1] = *(const h8*)(Ahi + off + 8);
        pA[2] = *(const h8*)(Alo + off); pA[3] = *(const h8*)(Alo + off + 8);
        #pragma unroll
        for (int s = 0; s < 2; ++s)
            #pragma unroll
            for (int nf = 0; nf < 4; ++nf) {
                const _Float16* bp = wf + ((size_t)((gbb + nf) * 32 + s) * 2) * 512 + lane * 8;
                BhA[s * 4 + nf] = *(const h8*)bp;
                BlA[s * 4 + nf] = *(const h8*)(bp + 512);
            }
    }

#define F_SI(SI, BHU, BLU, BHF, BLF)                                           \
    {                                                                          \
        __syncthreads();                                                       \
        *(h8*)(&lds[0][r * 72 + kh])     = pA[0];                              \
        *(h8*)(&lds[0][r * 72 + kh + 8]) = pA[1];                              \
        *(h8*)(&lds[1][r * 72 + kh])     = pA[2];                              \
        *(h8*)(&lds[1][r * 72 + kh + 8]) = pA[3];                              \
        __syncthreads();                                                       \
        {                                                                      \
            int sn = ((SI) + 1 < 16) ? (SI) + 1 : (SI);                        \
            size_t off = (size_t)(bm + r) * lda + (sn << 6) + kh;              \
            pA[0] = *(const h8*)(Ahi + off); pA[1] = *(const h8*)(Ahi + off + 8); \
            pA[2] = *(const h8*)(Alo + off); pA[3] = *(const h8*)(Alo + off + 8); \
            int ksb = sn << 1;                                                 \
            _Pragma("unroll")                                                  \
            for (int s = 0; s < 2; ++s)                                        \
                _Pragma("unroll")                                              \
                for (int nf = 0; nf < 4; ++nf) {                               \
                    const _Float16* bp = wf +                                  \
                        ((size_t)((gbb + nf) * 32 + ksb + s) * 2) * 512 + lane * 8; \
                    BHF[s * 4 + nf] = *(const h8*)bp;                          \
                    BLF[s * 4 + nf] = *(const h8*)(bp + 512);                  \
                }                                                              \
        }                                                                      \
        _Pragma("unroll")                                                      \
        for (int s = 0; s < 2; ++s) {                                          \
            h8 axh[2], axl[2];                                                 \
            _Pragma("unroll")                                                  \
            for (int mi = 0; mi < 2; ++mi) {                                   \
                int row = (wm << 5) + (mi << 4) + l15;                         \
                axh[mi] = *(const h8*)(&lds[0][row * 72 + s * 32 + quad * 8]); \
                axl[mi] = *(const h8*)(&lds[1][row * 72 + s * 32 + quad * 8]); \
            }                                                                  \
            _Pragma("unroll")                                                  \
            for (int nf = 0; nf < 4; ++nf)                                     \
                _Pragma("unroll")                                              \
                for (int mi = 0; mi < 2; ++mi) {                               \
                    acc[mi][nf] = MFMA16(axh[mi], BHU[s * 4 + nf], acc[mi][nf]); \
                    acc[mi][nf] = MFMA16(axh[mi], BLU[s * 4 + nf], acc[mi][nf]); \
                    acc[mi][nf] = MFMA16(axl[mi], BHU[s * 4 + nf], acc[mi][nf]); \
                }                                                              \
        }                                                                      \
    }

    for (int si = 0; si < 16; si += 2) {
        F_SI(si,     BhA, BlA, BhB, BlB);
        F_SI(si + 1, BhB, BlB, BhA, BlA);
    }
#undef F_SI

    #pragma unroll
    for (int nf = 0; nf < 4; ++nf) {
        int col = bn + (wn << 6) + (nf << 4) + l15;
        float bv = bias[col];
        #pragma unroll
        for (int mi = 0; mi < 2; ++mi) {
            #pragma unroll
            for (int rr = 0; rr < 4; ++rr) {
                int m = bm + (wm << 5) + (mi << 4) + (quad << 2) + rr;
                float v = acc[mi][nf][rr] + bv;
                size_t ro = (size_t)m * ldy + col;
                if (yhi) {
                    _Float16 hh = (_Float16)v;
                    yhi[ro] = hh;
                    ylo[ro] = (_Float16)(v - (float)hh);
                } else {
                    Y[ro] = v;
                }
            }
        }
    }
}

// ---------------------------------------------------------------------------
// Fused split-f16 MFMA LSTM step, 64x128 block, 2(m)x2(n) wave grid.
// lin bits: [z(1) | jt_hi(2) | bt(2) | jt_lo(3)] -> bt duplicates share lin%8
// (co-XCD weight reuse). Encoder grid 256 (z in {0,1}, wavefront fusion);
// decoder grid 128 (z=0). Block: 64 batch x (32 j x 4 gates); wave: 32 batch
// (2 m-frags) x (16 j x 4 gates); nf = gate -> all gates in-lane for epilogue.
// ---------------------------------------------------------------------------
struct LstmSet {
    const _Float16 *xhi, *xlo; long long ldx;
    const _Float16 *hphi, *hplo;
    const _Float16 *wf;
    const float *bih, *bhh;
    float *c;
    _Float16 *hohi, *holo;
};

__global__ __launch_bounds__(256, 2) void lstm_mfma6(LstmSet s0, LstmSet s1)
{
    const int lin = blockIdx.x;
    const int jt  = (lin & 7) | (((lin >> 5) & 3) << 3);   // 0..31
    const int bt  = (lin >> 3) & 3;
    LstmSet s = (lin >> 7) ? s1 : s0;
    if (s.wf == nullptr) return;
    __shared__ _Float16 lds[2][64 * 72];
    const int tid  = threadIdx.x;
    const int bm   = bt << 6;
    const int lane = tid & 63, wv = tid >> 6;
    const int wm   = wv >> 1, wn = wv & 1;
    const int l15  = lane & 15, quad = lane >> 4;
    const int r    = tid >> 2, kh = (tid & 3) << 4;
    const int jg   = (jt << 1) + wn;                       // 0..63

    f32x4 acc[2][4];
    #pragma unroll
    for (int mi = 0; mi < 2; ++mi)
        #pragma unroll
        for (int nf = 0; nf < 4; ++nf) acc[mi][nf] = (f32x4){0.f, 0.f, 0.f, 0.f};

    h8 pA[4];
    h8 BhA[8], BlA[8], BhB[8], BlB[8];
    {
        size_t off = (size_t)(bm + r) * s.ldx + kh;
        pA[0] = *(const h8*)(s.xhi + off); pA[1] = *(const h8*)(s.xhi + off + 8);
        pA[2] = *(const h8*)(s.xlo + off); pA[3] = *(const h8*)(s.xlo + off + 8);
        #pragma unroll
        for (int ss = 0; ss < 2; ++ss)
            #pragma unroll
            for (int nf = 0; nf < 4; ++nf) {
                const _Float16* bp = s.wf +
                    ((size_t)((nf * 64 + jg) * 32 + ss) * 2) * 512 + lane * 8;
                BhA[ss * 4 + nf] = *(const h8*)bp;
                BlA[ss * 4 + nf] = *(const h8*)(bp + 512);
            }
    }

#define L6_SI(SI, BHU, BLU, BHF, BLF)                                          \
    {                                                                          \
        __syncthreads();                                                       \
        *(h8*)(&lds[0][r * 72 + kh])     = pA[0];                              \
        *(h8*)(&lds[0][r * 72 + kh + 8]) = pA[1];                              \
        *(h8*)(&lds[1][r * 72 + kh])     = pA[2];                              \
        *(h8*)(&lds[1][r * 72 + kh + 8]) = pA[3];                              \
        __syncthreads();                                                       \
        {                                                                      \
            int sn  = ((SI) + 1 < 32) ? (SI) + 1 : (SI);                       \
            int phx = sn >> 4;                                                 \
            const _Float16* xh = phx ? s.hphi : s.xhi;                         \
            const _Float16* xl = phx ? s.hplo : s.xlo;                         \
            long long ld = phx ? Hn : s.ldx;                                   \
            size_t off = (size_t)(bm + r) * ld + ((sn & 15) << 6) + kh;        \
            pA[0] = *(const h8*)(xh + off); pA[1] = *(const h8*)(xh + off + 8);\
            pA[2] = *(const h8*)(xl + off); pA[3] = *(const h8*)(xl + off + 8);\
            const _Float16* wb = s.wf + (size_t)(sn >> 4) * WFRAG_4096;        \
            int ksb = (sn & 15) << 1;                                          \
            _Pragma("unroll")                                                  \
            for (int ss = 0; ss < 2; ++ss)                                     \
                _Pragma("unroll")                                              \
                for (int nf = 0; nf < 4; ++nf) {                               \
                    const _Float16* bp = wb +                                  \
                        ((size_t)((nf * 64 + jg) * 32 + ksb + ss) * 2) * 512   \
                        + lane * 8;                                            \
                    BHF[ss * 4 + nf] = *(const h8*)bp;                         \
                    BLF[ss * 4 + nf] = *(const h8*)(bp + 512);                 \
                }                                                              \
        }                                                                      \
        _Pragma("unroll")                                                      \
        for (int ss = 0; ss < 2; ++ss) {                                       \
            h8 axh[2], axl[2];                                                 \
            _Pragma("unroll")                                                  \
            for (int mi = 0; mi < 2; ++mi) {                                   \
                int row = (wm << 5) + (mi << 4) + l15;                         \
                axh[mi] = *(const h8*)(&lds[0][row * 72 + ss * 32 + quad * 8]);\
                axl[mi] = *(const h8*)(&lds[1][row * 72 + ss * 32 + quad * 8]);\
            }                                                                  \
            _Pragma("unroll")                                                  \
            for (int nf = 0; nf < 4; ++nf)                                     \
                _Pragma("unroll")                                              \
                for (int mi = 0; mi < 2; ++mi) {                               \
                    acc[mi][nf] = MFMA16(axh[mi], BHU[ss * 4 + nf], acc[mi][nf]); \
                    acc[mi][nf] = MFMA16(axh[mi], BLU[ss * 4 + nf], acc[mi][nf]); \
                    acc[mi][nf] = MFMA16(axl[mi], BHU[ss * 4 + nf], acc[mi][nf]); \
                }                                                              \
        }                                                                      \
    }

    for (int si = 0; si < 32; si += 2) {
        L6_SI(si,     BhA, BlA, BhB, BlB);
        L6_SI(si + 1, BhB, BlB, BhA, BlA);
    }
#undef L6_SI

    // Epilogue: lane holds all 4 gates (nf) for 2x4 batch rows x col j.
    float bs[4];
    #pragma unroll
    for (int nf = 0; nf < 4; ++nf) {
        int br = nf * Hn + (jg << 4) + l15;
        bs[nf] = s.bih[br] + s.bhh[br];
    }
    #pragma unroll
    for (int mi = 0; mi < 2; ++mi) {
        #pragma unroll
        for (int rr = 0; rr < 4; ++rr) {
            int m = (wm << 5) + (mi << 4) + (quad << 2) + rr;
            size_t idx = (size_t)(bm + m) * Hn + (jg << 4) + l15;
            float gi = acc[mi][0][rr] + bs[0];
            float gf = acc[mi][1][rr] + bs[1];
            float gg = acc[mi][2][rr] + bs[2];
            float go = acc[mi][3][rr] + bs[3];
            float cv = s.c[idx];
            float si_ = 1.0f / (1.0f + expf(-gi));
            float sf  = 1.0f / (1.0f + expf(-gf));
            float so  = 1.0f / (1.0f + expf(-go));
            float cn = sf * cv + si_ * tanhf(gg);
            float hn = so * tanhf(cn);
            s.c[idx] = cn;
            _Float16 hh = (_Float16)hn;
            s.hohi[idx] = hh;
            s.holo[idx] = (_Float16)(hn - (float)hh);
        }
    }
}

// ---------------------------------------------------------------------------
// Per-row top-k over V=16384; decoded indices + next-step embedding planes.
// ---------------------------------------------------------------------------
__global__ __launch_bounds__(256) void beam_kernel(
    const float* __restrict__ scores, float* __restrict__ decoded,
    _Float16* __restrict__ embhi, _Float16* __restrict__ emblo,
    const float* __restrict__ fqw_w, const float* __restrict__ fqw_b,
    const float* __restrict__ fql_w, const float* __restrict__ fql_b,
    int step, int kcur)
{
    __shared__ float svals[256];
    __shared__ int   sidx[256];
    __shared__ int   sel[Kn];
    const int b   = blockIdx.x;
    const int tid = threadIdx.x;
    const float* row = scores + (size_t)b * Vn;

    for (int rr = 0; rr < kcur; ++rr) {
        float best = -INFINITY;
        int   bidx = Vn;
        for (int i = tid; i < Vn; i += 256) {
            bool skip = false;
            for (int q = 0; q < rr; ++q) if (sel[q] == i) skip = true;
            float v = row[i];
            if (!skip && v > best) { best = v; bidx = i; }
        }
        svals[tid] = best; sidx[tid] = bidx;
        __syncthreads();
        for (int s = 128; s > 0; s >>= 1) {
            if (tid < s) {
                float v2 = svals[tid + s]; int i2 = sidx[tid + s];
                if (v2 > svals[tid] || (v2 == svals[tid] && i2 < sidx[tid])) {
                    svals[tid] = v2; sidx[tid] = i2;
                }
            }
            __syncthreads();
        }
        if (tid == 0) sel[rr] = sidx[0];
        __syncthreads();
    }

    if (tid < kcur) {
        int s_ = sel[tid];
        int fw = s_ / QLn, fl = s_ % QLn;
        float* dp = decoded + ((size_t)(b * DELTAn + step) * Kn + tid) * 2;
        dp[0] = (float)fl;
        dp[1] = (float)fw;
    }

    const int fw0 = sel[0] / QLn;
    const int fl0 = sel[0] % QLn;
    for (int o = tid; o < 512; o += 256) {
        float v0 = fqw_w[o * QLn + fw0] + fqw_b[o];
        float v1 = fql_w[o * QLn + fl0] + fql_b[o];
        _Float16 h0 = (_Float16)v0;
        _Float16 h1 = (_Float16)v1;
        size_t i0 = (size_t)b * Hn + o;
        embhi[i0]       = h0; emblo[i0]       = (_Float16)(v0 - (float)h0);
        embhi[i0 + 512] = h1; emblo[i0 + 512] = (_Float16)(v1 - (float)h1);
    }
}

// ---------------------------------------------------------------------------
extern "C" void kernel_launch(void* const* d_in, const int* in_sizes, int n_in,
                              void* d_out, int out_size, void* d_ws, size_t ws_size,
                              hipStream_t stream)
{
    int ii = 0;
    const float* x       = (const float*)d_in[ii++];
    const float* efc1_w  = (const float*)d_in[ii++];
    const float* efc1_b  = (const float*)d_in[ii++];
    const float* efc2_w  = (const float*)d_in[ii++];
    const float* efc2_b  = (const float*)d_in[ii++];
    const float* efc3_w  = (const float*)d_in[ii++];
    const float* efc3_b  = (const float*)d_in[ii++];
    const float* el1_wih = (const float*)d_in[ii++];
    const float* el1_whh = (const float*)d_in[ii++];
    const float* el1_bih = (const float*)d_in[ii++];
    const float* el1_bhh = (const float*)d_in[ii++];
    const float* el2_wih = (const float*)d_in[ii++];
    const float* el2_whh = (const float*)d_in[ii++];
    const float* el2_bih = (const float*)d_in[ii++];
    const float* el2_bhh = (const float*)d_in[ii++];
    const float* dl1_wih = (const float*)d_in[ii++];
    const float* dl1_whh = (const float*)d_in[ii++];
    const float* dl1_bih = (const float*)d_in[ii++];
    const float* dl1_bhh = (const float*)d_in[ii++];
    const float* dl2_wih = (const float*)d_in[ii++];
    const float* dl2_whh = (const float*)d_in[ii++];
    const float* dl2_bih = (const float*)d_in[ii++];
    const float* dl2_bhh = (const float*)d_in[ii++];
    const float* dfc1_w  = (const float*)d_in[ii++];
    const float* dfc1_b  = (const float*)d_in[ii++];
    const float* dfc2_w  = (const float*)d_in[ii++];
    const float* dfc2_b  = (const float*)d_in[ii++];
    const float* dfc3_w  = (const float*)d_in[ii++];
    const float* dfc3_b  = (const float*)d_in[ii++];
    const float* fqw_w   = (const float*)d_in[ii++];
    const float* fqw_b   = (const float*)d_in[ii++];
    const float* fql_w   = (const float*)d_in[ii++];
    const float* fql_b   = (const float*)d_in[ii++];

    float* out = (float*)d_out;

    // ---- Workspace layout (~245 MB) ----
    char* p = (char*)d_ws;
    auto alloc = [&](size_t bytes) { char* q = p; p += (bytes + 255) & ~(size_t)255; return q; };
    _Float16* bufhi = (_Float16*)alloc((size_t)32768 * 1024 * 2);  // e3 hi; later dfc3' frags
    _Float16* buflo = (_Float16*)alloc((size_t)32768 * 1024 * 2);  // e3 lo (dfc3' spillover)
    _Float16* slot0 = (_Float16*)alloc((size_t)2 * WFRAG_4096 * 2); // l1 frags
    _Float16* slot1 = (_Float16*)alloc((size_t)2 * WFRAG_4096 * 2); // l2 frags
    _Float16* efw2  = (_Float16*)alloc((size_t)2097152 * 2);        // efc2' frags
    _Float16* efw3  = (_Float16*)alloc((size_t)2097152 * 2);        // efc3' frags
    _Float16* dfw1  = (_Float16*)alloc((size_t)2097152 * 2);        // dfc1' frags
    _Float16* dfw2  = (_Float16*)alloc((size_t)2097152 * 2);        // dfc2' frags
    float*    scores= (float*)alloc((size_t)256 * Vn * 4);          // fp32; t1 planes in FC
    char*  zbase = p;                                               // zero block:
    float* c1    = (float*)alloc((size_t)256 * Hn * 4);
    float* c2    = (float*)alloc((size_t)256 * Hn * 4);
    _Float16* h1hiA = (_Float16*)alloc((size_t)256 * Hn * 2);
    _Float16* h1loA = (_Float16*)alloc((size_t)256 * Hn * 2);
    _Float16* h2hiA = (_Float16*)alloc((size_t)256 * Hn * 2);
    _Float16* h2loA = (_Float16*)alloc((size_t)256 * Hn * 2);
    size_t zbytes = (size_t)(p - zbase);
    _Float16* h1hiB = (_Float16*)alloc((size_t)256 * Hn * 2);
    _Float16* h1loB = (_Float16*)alloc((size_t)256 * Hn * 2);
    _Float16* h2hiB = (_Float16*)alloc((size_t)256 * Hn * 2);
    _Float16* h2loB = (_Float16*)alloc((size_t)256 * Hn * 2);
    _Float16* f1hi  = (_Float16*)alloc((size_t)256 * Hn * 2);
    _Float16* f1lo  = (_Float16*)alloc((size_t)256 * Hn * 2);
    _Float16* f2hi  = (_Float16*)alloc((size_t)256 * Hn * 2);
    _Float16* f2lo  = (_Float16*)alloc((size_t)256 * Hn * 2);
    _Float16* embhi = (_Float16*)alloc((size_t)256 * Hn * 2);
    _Float16* emblo = (_Float16*)alloc((size_t)256 * Hn * 2);

    // FC-phase temps (regions dead during FC):
    _Float16* t1hi = (_Float16*)scores;            // 4096x1024 planes in scores
    _Float16* t1lo = t1hi + (size_t)4096 * 1024;
    _Float16* t2hi = slot0;                        // 4096x1024 planes in slot0
    _Float16* t2lo = t2hi + (size_t)4096 * 1024;
    _Float16* dfc3f = bufhi;                       // dfc3' frags (67.1 MB)

    const long long TH = (long long)Tn * Hn;

    // ---- efc2'/efc3' fragment conversion ----
    hipLaunchKernelGGL(wconv_frag, dim3(512), dim3(256), 0, stream, efc2_w, efw2, 64);
    hipLaunchKernelGGL(wconv_frag, dim3(512), dim3(256), 0, stream, efc3_w, efw3, 64);

    // ---- Encoder FC chain, 8 chunks of 4096 rows ----
    for (int c = 0; c < 8; ++c) {
        const float* xc = x + (size_t)c * 4096 * 64;
        size_t ofs = (size_t)c * 4096 * 1024;
        hipLaunchKernelGGL(gemm_nt_128, dim3(8, 32), dim3(256), 0, stream,
                           xc, 64, efc1_w, 64, efc1_b, t1hi, t1lo, Hn);
        hipLaunchKernelGGL(mm64x128, dim3(8, 64), dim3(256), 0, stream,
                           t1hi, t1lo, (long long)Hn, efw2, efc2_b,
                           (float*)nullptr, (long long)Hn, t2hi, t2lo);
        hipLaunchKernelGGL(mm64x128, dim3(8, 64), dim3(256), 0, stream,
                           t2hi, t2lo, (long long)Hn, efw3, efc3_b,
                           (float*)nullptr, (long long)Hn, bufhi + ofs, buflo + ofs);
    }

    // ---- Encoder LSTM weight frags ----
    hipLaunchKernelGGL(wconv_frag, dim3(2048), dim3(256), 0, stream, el1_wih, slot0, 256);
    hipLaunchKernelGGL(wconv_frag, dim3(2048), dim3(256), 0, stream, el1_whh, slot0 + WFRAG_4096, 256);
    hipLaunchKernelGGL(wconv_frag, dim3(2048), dim3(256), 0, stream, el2_wih, slot1, 256);
    hipLaunchKernelGGL(wconv_frag, dim3(2048), dim3(256), 0, stream, el2_whh, slot1 + WFRAG_4096, 256);

    hipMemsetAsync(zbase, 0, zbytes, stream);

    // ---- Encoder LSTMs: wavefront-fused l1(t=d) + l2(t=d-1), grid 256 ----
    _Float16 *h1hiC = h1hiA, *h1loC = h1loA, *h1hiN = h1hiB, *h1loN = h1loB;
    _Float16 *h2hiC = h2hiA, *h2loC = h2loA, *h2hiN = h2hiB, *h2loN = h2loB;
    _Float16* tp;
    for (int d = 0; d <= Tn; ++d) {
        LstmSet s0 = {}, s1 = {};
        if (d < Tn) {
            s0.xhi = bufhi + (size_t)d * Hn; s0.xlo = buflo + (size_t)d * Hn; s0.ldx = TH;
            s0.hphi = h1hiC; s0.hplo = h1loC; s0.wf = slot0;
            s0.bih = el1_bih; s0.bhh = el1_bhh; s0.c = c1;
            s0.hohi = h1hiN; s0.holo = h1loN;
        }
        if (d >= 1) {
            s1.xhi = h1hiC; s1.xlo = h1loC; s1.ldx = Hn;
            s1.hphi = h2hiC; s1.hplo = h2loC; s1.wf = slot1;
            s1.bih = el2_bih; s1.bhh = el2_bhh; s1.c = c2;
            s1.hohi = h2hiN; s1.holo = h2loN;
        }
        hipLaunchKernelGGL(lstm_mfma6, dim3(256), dim3(256), 0, stream, s0, s1);
        if (d < Tn)  { tp = h1hiC; h1hiC = h1hiN; h1hiN = tp;
                       tp = h1loC; h1loC = h1loN; h1loN = tp; }
        if (d >= 1)  { tp = h2hiC; h2hiC = h2hiN; h2hiN = tp;
                       tp = h2loC; h2loC = h2loN; h2loN = tp; }
    }

    // ---- Decoder weight frags ----
    hipLaunchKernelGGL(wconv_frag, dim3(2048), dim3(256), 0, stream, dl1_wih, slot0, 256);
    hipLaunchKernelGGL(wconv_frag, dim3(2048), dim3(256), 0, stream, dl1_whh, slot0 + WFRAG_4096, 256);
    hipLaunchKernelGGL(wconv_frag, dim3(2048), dim3(256), 0, stream, dl2_wih, slot1, 256);
    hipLaunchKernelGGL(wconv_frag, dim3(2048), dim3(256), 0, stream, dl2_whh, slot1 + WFRAG_4096, 256);
    hipLaunchKernelGGL(wconv_frag, dim3(8192), dim3(256), 0, stream, dfc3_w, dfc3f, 1024);
    hipLaunchKernelGGL(wconv_frag, dim3(512), dim3(256), 0, stream, dfc1_w, dfw1, 64);
    hipLaunchKernelGGL(wconv_frag, dim3(512), dim3(256), 0, stream, dfc2_w, dfw2, 64);

    hipMemsetAsync(out, 0, (size_t)out_size * sizeof(float), stream);

    // ---- Decoder: 16 autoregressive steps ----
    for (int it = 0; it < DELTAn; ++it) {
        LstmSet s0 = {}, sx = {};
        s0.xhi = (it == 0) ? h2hiC : embhi;
        s0.xlo = (it == 0) ? h2loC : emblo;
        s0.ldx = Hn;
        s0.hphi = h1hiC; s0.hplo = h1loC; s0.wf = slot0;
        s0.bih = dl1_bih; s0.bhh = dl1_bhh; s0.c = c1;
        s0.hohi = h1hiN; s0.holo = h1loN;
        hipLaunchKernelGGL(lstm_mfma6, dim3(128), dim3(256), 0, stream, s0, sx);
        tp = h1hiC; h1hiC = h1hiN; h1hiN = tp;
        tp = h1loC; h1loC = h1loN; h1loN = tp;

        LstmSet s2 = {};
        s2.xhi = h1hiC; s2.xlo = h1loC; s2.ldx = Hn;
        s2.hphi = h2hiC; s2.hplo = h2loC; s2.wf = slot1;
        s2.bih = dl2_bih; s2.bhh = dl2_bhh; s2.c = c2;
        s2.hohi = h2hiN; s2.holo = h2loN;
        hipLaunchKernelGGL(lstm_mfma6, dim3(128), dim3(256), 0, stream, s2, sx);
        tp = h2hiC; h2hiC = h2hiN; h2hiN = tp;
        tp = h2loC; h2loC = h2loN; h2loN = tp;

        // Decoder FC chain (split-f16 MFMA, plane dataflow)
        hipLaunchKernelGGL(gemm_mfma_s, dim3(16, 4), dim3(256), 0, stream,
                           h2hiC, h2loC, (long long)Hn, dfw1, dfc1_b,
                           f1hi, f1lo, (long long)Hn);
        hipLaunchKernelGGL(gemm_mfma_s, dim3(16, 4), dim3(256), 0, stream,
                           f1hi, f1lo, (long long)Hn, dfw2, dfc2_b,
                           f2hi, f2lo, (long long)Hn);
        hipLaunchKernelGGL(mm64x128, dim3(128, 4), dim3(256), 0, stream,
                           f2hi, f2lo, (long long)Hn, dfc3f, dfc3_b,
                           scores, (long long)Vn, (_Float16*)nullptr, (_Float16*)nullptr);
        hipLaunchKernelGGL(beam_kernel, dim3(Bn), dim3(256), 0, stream,
                           scores, out, embhi, emblo, fqw_w, fqw_b, fql_w, fql_b,
                           it, (it == 0) ? Kn : 1);
    }
}